// Round 8
// baseline (295.345 us; speedup 1.0000x reference)
//
#include <hip/hip_runtime.h>
#include <math.h>

#define B     4096
#define ND    13
#define NS    26
#define NF    39
#define VOCAB 100000
#define NP    351      // l<=m pairs in 26x26
#define NCH   16       // CIN chunks
#define CHP   23       // p's per chunk
#define NPP   368      // NCH*CHP, pad zeroed
#define GSTR  28       // Gst row: [0..25]=Gs_j, [26]=A1s, [27]=lut bits
#define RPB   2        // rows per block
#define NT    256
#define XSS   212

// ---------------- workspace layout (floats) ----------------
#define OFF_GST 0        // 368*28 = 10304
#define OFF_CST 10304    // 1
#define OFF_C2J 10312    // 26

// ---- merged precompute kernel, 28 independent blocks ----
__global__ __launch_bounds__(256) void k_pre(const float* __restrict__ W0,
                                             const float* __restrict__ W1,
                                             const float* __restrict__ b0,
                                             const float* __restrict__ b1,
                                             const float* __restrict__ clw,
                                             float* __restrict__ Gst,
                                             float* __restrict__ cst,
                                             float* __restrict__ c2j) {
    int blk = blockIdx.x, tid = threadIdx.x;
    if (blk < 26) {
        int j = blk;
        __shared__ float vh[2][128];
        __shared__ float vj[128];
        __shared__ float c2r[2];
        {
            int i = tid & 127, h = tid >> 7;
            const float* wp = W1 + (long)(h * 64) * 3328 + i * 26 + j;
            float acc = 0.f;
#pragma unroll 8
            for (int o = 0; o < 64; o++) acc += clw[128 + h * 64 + o] * wp[o * 3328];
            vh[h][i] = acc;
        }
        __syncthreads();
        if (tid < 128) {
            float vv = vh[0][tid] + vh[1][tid];
            vj[tid] = vv;
            float c = vv * b0[tid];
            for (int off = 32; off; off >>= 1) c += __shfl_down(c, off, 64);
            if ((tid & 63) == 0) c2r[tid >> 6] = c;
        }
        __syncthreads();
        if (tid == 0) c2j[j] = c2r[0] + c2r[1];
        for (int p = tid; p < NPP; p += 256) {
            float g = 0.f;
            if (p < NP) {
                int l = 0, rem = p;
                while (rem >= NS - l) { rem -= NS - l; l++; }
                int m = l + rem;
                float sym = (l != m) ? 1.f : 0.f;
                const float* wa = W0 + l * 26 + m;
                const float* wb = W0 + m * 26 + l;
#pragma unroll 8
                for (int i = 0; i < 128; i++)
                    g += vj[i] * (wa[i * 676] + sym * wb[i * 676]);
            }
            Gst[p * GSTR + j] = g;
        }
    } else if (blk == 26) {
        for (int p = tid; p < NPP; p += 256) {
            float a = 0.f; int lmbits = 0;
            if (p < NP) {
                int l = 0, rem = p;
                while (rem >= NS - l) { rem -= NS - l; l++; }
                int m = l + rem;
                float sym = (l != m) ? 1.f : 0.f;
                const float* wa = W0 + l * 26 + m;
                const float* wb = W0 + m * 26 + l;
#pragma unroll 8
                for (int o = 0; o < 128; o++)
                    a += clw[o] * (wa[o * 676] + sym * wb[o * 676]);
                lmbits = (l << 5) | m;
            }
            Gst[p * GSTR + 26] = a;
            Gst[p * GSTR + 27] = __int_as_float(lmbits);
        }
    } else {
        __shared__ float red[2];
        float c = 0.f;
        if (tid < 128) {
            c = clw[tid] * b0[tid] + clw[128 + tid] * b1[tid];
            for (int off = 32; off; off >>= 1) c += __shfl_down(c, off, 64);
            if ((tid & 63) == 0) red[tid >> 6] = c;
        }
        __syncthreads();
        if (tid == 0) cst[0] = 8.f * (red[0] + red[1]);
    }
}

// ---- fused main: gather + linear + CIN + DNN. 2 rows/block, grid 2048. ----
// 16 CIN chunks of 23 p's; lane = (cg<<4) + (r<<3) + k; all 64 lanes active.
__global__ __launch_bounds__(NT, 6) void k_main(
    const float* __restrict__ inputs, const float* __restrict__ tables,
    const float* __restrict__ lW, const float* __restrict__ lb,
    const float* __restrict__ Gst, const float* __restrict__ c2j,
    const float* __restrict__ cst,
    const float* __restrict__ dW1, const float* __restrict__ db1,
    const float* __restrict__ dW2, const float* __restrict__ db2,
    const float* __restrict__ dW3, const float* __restrict__ db3,
    const float* __restrict__ dW4, const float* __restrict__ db4,
    const float* __restrict__ clb,
    float* __restrict__ out) {
    __shared__ float insf[RPB][40];      // 320 B
    __shared__ float xs[RPB][XSS];       // 1.7 KB  emb, CIN layout
    __shared__ float inT[224][RPB];      // 1.8 KB  DNN input transposed
    __shared__ float h1T[256][RPB];      // 2 KB
    __shared__ float h2T[128][RPB];      // 1 KB
    __shared__ float h3T[64][RPB];       // 0.5 KB
    __shared__ float ps[256][RPB];       // 2 KB    split-K partials
    __shared__ float lin_s[RPB], scin_s[RPB];
    __shared__ float redbuf[4][RPB];

    int tid = threadIdx.x;
    int b0r = blockIdx.x * RPB;

    // phase 1: raw inputs
    if (tid < RPB * NF) {
        int r = tid / NF, c = tid - r * NF;
        insf[r][c] = inputs[(b0r + r) * NF + c];
    }
    __syncthreads();

    // phase 2: gather embeddings (both layouts) + dense cols + linear term
    if (tid < RPB * NS * 2) {
        int t = tid >> 1, h = tid & 1;
        int r = t / NS, f = t - r * NS;
        int idx = (int)insf[r][ND + f];
        float4 v = *(const float4*)(tables + ((long)f * VOCAB + idx) * 8 + h * 4);
        *(float4*)&xs[r][f * 8 + h * 4] = v;
        int cb = ND + f * 8 + h * 4;
        inT[cb + 0][r] = v.x; inT[cb + 1][r] = v.y;
        inT[cb + 2][r] = v.z; inT[cb + 3][r] = v.w;
    } else if (tid >= 128 && tid < 128 + RPB * ND) {
        int t = tid - 128;
        int r = t / ND, c = t - r * ND;
        inT[c][r] = insf[r][c];
    } else if (tid >= 192 && tid < 192 + RPB) {
        int r = tid - 192;
        float acc = lb[0];
        for (int c = 0; c < NF; c++) acc += insf[r][c] * lW[c];
        lin_s[r] = acc;
    }
    __syncthreads();

    // phase 3: CIN. chunk = w*4 + cg; 23 p's each; t[27] accumulators.
    {
        int lane = tid & 63, w = tid >> 6;
        int k = lane & 7, r = (lane >> 3) & 1, cg = lane >> 4;
        int chunk = w * 4 + cg;
        const float* gr = Gst + chunk * (CHP * GSTR);
        const float* xrow = &xs[r][0];
        float t[27];
#pragma unroll
        for (int j = 0; j < 27; j++) t[j] = 0.f;
        for (int pi = 0; pi < CHP; pi++) {
            const float4* g4 = (const float4*)(gr + pi * GSTR);
            float4 g6 = g4[6];
            int lm = __float_as_int(g6.w);
            float q = xrow[(lm >> 5) * 8 + k] * xrow[(lm & 31) * 8 + k];
            float4 g0 = g4[0], g1 = g4[1], g2 = g4[2];
            float4 g3 = g4[3], g4v = g4[4], g5 = g4[5];
            t[0]  += g0.x * q;  t[1]  += g0.y * q;  t[2]  += g0.z * q;  t[3]  += g0.w * q;
            t[4]  += g1.x * q;  t[5]  += g1.y * q;  t[6]  += g1.z * q;  t[7]  += g1.w * q;
            t[8]  += g2.x * q;  t[9]  += g2.y * q;  t[10] += g2.z * q;  t[11] += g2.w * q;
            t[12] += g3.x * q;  t[13] += g3.y * q;  t[14] += g3.z * q;  t[15] += g3.w * q;
            t[16] += g4v.x * q; t[17] += g4v.y * q; t[18] += g4v.z * q; t[19] += g4v.w * q;
            t[20] += g5.x * q;  t[21] += g5.y * q;  t[22] += g5.z * q;  t[23] += g5.w * q;
            t[24] += g6.x * q;  t[25] += g6.y * q;  t[26] += g6.z * q;
        }
        float csel = (chunk == 0) ? 1.f : 0.f;
        float part = t[26];
#pragma unroll
        for (int j = 0; j < 26; j++)
            part += (t[j] + csel * c2j[j]) * xrow[j * 8 + k];
        part += __shfl_xor(part, 1, 64);   // sum over k
        part += __shfl_xor(part, 2, 64);
        part += __shfl_xor(part, 4, 64);
        part += __shfl_xor(part, 16, 64);  // sum over cg
        part += __shfl_xor(part, 32, 64);
        if ((lane & 55) == 0) redbuf[w][r] = part;   // k==0 && cg==0
    }
    __syncthreads();

    // phase 4: scin finalize + DNN layer1 (221 -> 256)
    if (tid < RPB) {
        float s = cst[0];
#pragma unroll
        for (int w = 0; w < 4; w++) s += redbuf[w][tid];
        scin_s[tid] = s;
    }
    {
        float bias = db1[tid];
        float a0 = bias, a1 = bias;
#pragma unroll 4
        for (int c = 0; c < 221; c++) {
            float w = dW1[c * 256 + tid];
            float2 iv = *(const float2*)&inT[c][0];
            a0 += iv.x * w; a1 += iv.y * w;
        }
        h1T[tid][0] = fmaxf(a0, 0.f);
        h1T[tid][1] = fmaxf(a1, 0.f);
    }
    __syncthreads();

    // phase 5: layer2 (256 -> 128), split-K x2
    {
        int o = tid & 127, ks = tid >> 7;
        float a0 = 0.f, a1 = 0.f;
        const float* wb = dW2 + o;
#pragma unroll 4
        for (int cc = 0; cc < 128; cc++) {
            int c = ks * 128 + cc;
            float w = wb[c * 128];
            float2 iv = *(const float2*)&h1T[c][0];
            a0 += iv.x * w; a1 += iv.y * w;
        }
        ps[ks * 128 + o][0] = a0;
        ps[ks * 128 + o][1] = a1;
    }
    __syncthreads();
    if (tid < 128) {
        float bias = db2[tid];
        h2T[tid][0] = fmaxf(ps[tid][0] + ps[128 + tid][0] + bias, 0.f);
        h2T[tid][1] = fmaxf(ps[tid][1] + ps[128 + tid][1] + bias, 0.f);
    }
    __syncthreads();

    // phase 6: layer3 (128 -> 64), split-K x4
    {
        int o = tid & 63, ks = tid >> 6;
        float a0 = 0.f, a1 = 0.f;
        const float* wb = dW3 + o;
#pragma unroll 4
        for (int cc = 0; cc < 32; cc++) {
            int c = ks * 32 + cc;
            float w = wb[c * 64];
            float2 iv = *(const float2*)&h2T[c][0];
            a0 += iv.x * w; a1 += iv.y * w;
        }
        ps[ks * 64 + o][0] = a0;
        ps[ks * 64 + o][1] = a1;
    }
    __syncthreads();
    if (tid < 64) {
        float s0 = 0.f, s1 = 0.f;
#pragma unroll
        for (int ks = 0; ks < 4; ks++) {
            s0 += ps[ks * 64 + tid][0];
            s1 += ps[ks * 64 + tid][1];
        }
        float bias = db3[tid];
        h3T[tid][0] = fmaxf(s0 + bias, 0.f);
        h3T[tid][1] = fmaxf(s1 + bias, 0.f);
    }
    __syncthreads();

    // phase 7: layer4 (64 -> 1) + combine + sigmoid (wave 0)
    if (tid < 64) {
        float w4 = dW4[tid];
        float s0 = h3T[tid][0] * w4;
        float s1 = h3T[tid][1] * w4;
#pragma unroll
        for (int off = 1; off < 64; off <<= 1) {
            s0 += __shfl_xor(s0, off, 64);
            s1 += __shfl_xor(s1, off, 64);
        }
        if (tid == 0) {
            float sv[RPB] = { s0, s1 };
            float bb = db4[0], cb = clb[0];
#pragma unroll
            for (int r = 0; r < RPB; r++) {
                float dense = fmaxf(sv[r] + bb, 0.f);
                float cin = fmaxf(scin_s[r] + cb, 0.f);
                float x = lin_s[r] + cin + dense;
                out[b0r + r] = 1.f / (1.f + expf(-x));
            }
        }
    }
}

extern "C" void kernel_launch(void* const* d_in, const int* in_sizes, int n_in,
                              void* d_out, int out_size, void* d_ws, size_t ws_size,
                              hipStream_t stream) {
    const float* inputs = (const float*)d_in[0];
    const float* tables = (const float*)d_in[1];
    const float* lW     = (const float*)d_in[2];
    const float* lb     = (const float*)d_in[3];
    const float* W0     = (const float*)d_in[4];
    const float* b0     = (const float*)d_in[5];
    const float* W1c    = (const float*)d_in[6];
    const float* b1c    = (const float*)d_in[7];
    const float* clw    = (const float*)d_in[8];
    const float* clb    = (const float*)d_in[9];
    const float* dW1    = (const float*)d_in[10];
    const float* db1    = (const float*)d_in[11];
    const float* dW2    = (const float*)d_in[12];
    const float* db2    = (const float*)d_in[13];
    const float* dW3    = (const float*)d_in[14];
    const float* db3    = (const float*)d_in[15];
    const float* dW4    = (const float*)d_in[16];
    const float* db4    = (const float*)d_in[17];

    float* ws   = (float*)d_ws;
    float* Gst  = ws + OFF_GST;
    float* cst  = ws + OFF_CST;
    float* c2j  = ws + OFF_C2J;

    k_pre<<<28, 256, 0, stream>>>(W0, W1c, b0, b1c, clw, Gst, cst, c2j);
    k_main<<<B / RPB, NT, 0, stream>>>(inputs, tables, lW, lb, Gst, c2j, cst,
                                       dW1, db1, dW2, db2, dW3, db3, dW4, db4, clb,
                                       (float*)d_out);
}